// Round 1
// baseline (2769.864 us; speedup 1.0000x reference)
//
#include <hip/hip_runtime.h>

#define DD 64

// ---------------- degree / CSR build ----------------

__global__ __launch_bounds__(256) void count_deg_k(const int* __restrict__ dst, int* __restrict__ cnt, int E) {
  int e = blockIdx.x * 256 + threadIdx.x;
  if (e < E) atomicAdd(&cnt[dst[e]], 1);
}

__global__ __launch_bounds__(256) void dinv_k(const int* __restrict__ cnt, float* __restrict__ dinv, int n) {
  int i = blockIdx.x * 256 + threadIdx.x;
  if (i < n) dinv[i] = rsqrtf((float)cnt[i] + 1.0f);
}

// block scans 1024 elements (256 thr x 4); writes local-exclusive prefix + block total
__global__ __launch_bounds__(256) void scan_a_k(const int* __restrict__ cnt, int* __restrict__ out,
                                                int* __restrict__ bsums, int n) {
  __shared__ int ts[256];
  int t = threadIdx.x;
  int base = blockIdx.x * 1024 + t * 4;
  int c0 = 0, c1 = 0, c2 = 0, c3 = 0;
  if (base + 3 < n) {
    int4 v = *(const int4*)(cnt + base);
    c0 = v.x; c1 = v.y; c2 = v.z; c3 = v.w;
  } else {
    if (base + 0 < n) c0 = cnt[base + 0];
    if (base + 1 < n) c1 = cnt[base + 1];
    if (base + 2 < n) c2 = cnt[base + 2];
  }
  int s = c0 + c1 + c2 + c3;
  ts[t] = s;
  __syncthreads();
  for (int o = 1; o < 256; o <<= 1) {
    int v = 0;
    if (t >= o) v = ts[t - o];
    __syncthreads();
    ts[t] += v;
    __syncthreads();
  }
  int excl = ts[t] - s;
  if (base + 0 < n) out[base + 0] = excl;
  if (base + 1 < n) out[base + 1] = excl + c0;
  if (base + 2 < n) out[base + 2] = excl + c0 + c1;
  if (base + 3 < n) out[base + 3] = excl + c0 + c1 + c2;
  if (t == 255) bsums[blockIdx.x] = ts[255];
}

__global__ void scan_b_k(int* bsums, int nb) {
  if (threadIdx.x == 0 && blockIdx.x == 0) {
    int run = 0;
    for (int i = 0; i < nb; ++i) { int v = bsums[i]; bsums[i] = run; run += v; }
  }
}

__global__ __launch_bounds__(256) void scan_c_k(int* __restrict__ off, int* __restrict__ cursor,
                                                const int* __restrict__ bsums, int n, int E) {
  int i = blockIdx.x * 256 + threadIdx.x;
  if (i < n) {
    int v = off[i] + bsums[i >> 10];
    off[i] = v;
    cursor[i] = v;
  } else if (i == n) {
    off[n] = E;
  }
}

__global__ __launch_bounds__(256) void fill_csr_k(const int* __restrict__ src, const int* __restrict__ dst,
                                                  const float* __restrict__ dinv, int* __restrict__ cursor,
                                                  int2* __restrict__ csr, int E) {
  int e = blockIdx.x * 256 + threadIdx.x;
  if (e < E) {
    int s = src[e], d = dst[e];
    int pos = atomicAdd(&cursor[d], 1);
    float w = dinv[s] * dinv[d];
    csr[pos] = make_int2(s, __float_as_int(w));
  }
}

// ---------------- per-layer kernels ----------------

// out[row] = act(in[row]) @ W ; act = identity (layer 0) or relu(ln(.)) of previous layer
__global__ __launch_bounds__(256) void gemm_ln_k(const float* __restrict__ in, const float* __restrict__ W,
                                                 float* __restrict__ out, const float* __restrict__ lnw,
                                                 const float* __restrict__ lnb, const float* __restrict__ stats,
                                                 int applyLn, int n) {
  __shared__ float Wl[64 * 64];
  __shared__ float Al[64 * 68];  // stride 68: float4-aligned, 2-way bank alias only (free)
  int t = threadIdx.x;
#pragma unroll
  for (int i = 0; i < 4; ++i)
    ((float4*)Wl)[t + i * 256] = ((const float4*)W)[t + i * 256];
  float mean = 0.f, rstd = 1.f;
  if (applyLn) { mean = stats[0]; rstd = stats[1]; }
  int row0 = blockIdx.x * 64;
#pragma unroll
  for (int i = 0; i < 4; ++i) {
    int q = t + i * 256;         // float4 index within 64x64 tile
    int r = q >> 4, c4 = q & 15;
    int gr = row0 + r;
    float4 v = make_float4(0.f, 0.f, 0.f, 0.f);
    if (gr < n) v = ((const float4*)in)[(size_t)gr * 16 + c4];
    if (applyLn) {
      int c = c4 * 4;
      v.x = fmaxf(fmaf((v.x - mean) * rstd, lnw[c + 0], lnb[c + 0]), 0.f);
      v.y = fmaxf(fmaf((v.y - mean) * rstd, lnw[c + 1], lnb[c + 1]), 0.f);
      v.z = fmaxf(fmaf((v.z - mean) * rstd, lnw[c + 2], lnb[c + 2]), 0.f);
      v.w = fmaxf(fmaf((v.w - mean) * rstd, lnw[c + 3], lnb[c + 3]), 0.f);
    }
    *(float4*)&Al[r * 68 + c4 * 4] = v;
  }
  __syncthreads();
  int r = t >> 2, cb = (t & 3) * 16;
  float acc[16];
#pragma unroll
  for (int j = 0; j < 16; ++j) acc[j] = 0.f;
  for (int k = 0; k < 64; ++k) {
    float a = Al[r * 68 + k];
#pragma unroll
    for (int j = 0; j < 16; ++j) acc[j] = fmaf(a, Wl[k * 64 + cb + j], acc[j]);
  }
  int gr = row0 + r;
  if (gr < n) {
    float4* op = (float4*)&out[(size_t)gr * 64 + cb];
    op[0] = make_float4(acc[0], acc[1], acc[2], acc[3]);
    op[1] = make_float4(acc[4], acc[5], acc[6], acc[7]);
    op[2] = make_float4(acc[8], acc[9], acc[10], acc[11]);
    op[3] = make_float4(acc[12], acc[13], acc[14], acc[15]);
  }
}

// wave-per-node CSR gather + bias + self-loop; accumulates global sum/sumsq
__global__ __launch_bounds__(256) void agg_k(const float* __restrict__ hw, const int* __restrict__ off,
                                             const int2* __restrict__ csr, const float* __restrict__ dinv,
                                             const float* __restrict__ bias, float* __restrict__ out,
                                             double* __restrict__ sums, int n) {
  int wid = (int)((blockIdx.x * 256 + threadIdx.x) >> 6);
  int lane = threadIdx.x & 63;
  float s1 = 0.f, s2 = 0.f;
  if (wid < n) {
    float di = dinv[wid];
    float acc = fmaf(di * di, hw[(size_t)wid * 64 + lane], bias[lane]);
    int e0 = off[wid], e1 = off[wid + 1];
    for (int e = e0; e < e1; ++e) {
      int2 ew = csr[e];
      acc = fmaf(__int_as_float(ew.y), hw[(size_t)ew.x * 64 + lane], acc);
    }
    out[(size_t)wid * 64 + lane] = acc;
    s1 = acc;
    s2 = acc * acc;
  }
#pragma unroll
  for (int o = 32; o > 0; o >>= 1) {
    s1 += __shfl_down(s1, o);
    s2 += __shfl_down(s2, o);
  }
  __shared__ float red1[4], red2[4];
  int w = threadIdx.x >> 6;
  if (lane == 0) { red1[w] = s1; red2[w] = s2; }
  __syncthreads();
  if (threadIdx.x == 0) {
    double a = (double)red1[0] + (double)red1[1] + (double)red1[2] + (double)red1[3];
    double b = (double)red2[0] + (double)red2[1] + (double)red2[2] + (double)red2[3];
    atomicAdd(&sums[0], a);
    atomicAdd(&sums[1], b);
  }
}

__global__ void finalize_k(const double* __restrict__ sums, float* __restrict__ stats, int M) {
  double mean = sums[0] / M;
  double var = sums[1] / M - mean * mean;
  stats[0] = (float)mean;
  stats[1] = (float)rsqrt(var + 1e-5);
}

// final layer: in-place ln+relu on d_out
__global__ __launch_bounds__(256) void norm_relu_k(float* __restrict__ io, const float* __restrict__ lnw,
                                                   const float* __restrict__ lnb, const float* __restrict__ stats,
                                                   int n4) {
  int i = blockIdx.x * 256 + threadIdx.x;
  if (i >= n4) return;
  float mean = stats[0], rstd = stats[1];
  float4 v = ((float4*)io)[i];
  int c = (i & 15) * 4;
  v.x = fmaxf(fmaf((v.x - mean) * rstd, lnw[c + 0], lnb[c + 0]), 0.f);
  v.y = fmaxf(fmaf((v.y - mean) * rstd, lnw[c + 1], lnb[c + 1]), 0.f);
  v.z = fmaxf(fmaf((v.z - mean) * rstd, lnw[c + 2], lnb[c + 2]), 0.f);
  v.w = fmaxf(fmaf((v.w - mean) * rstd, lnw[c + 3], lnb[c + 3]), 0.f);
  ((float4*)io)[i] = v;
}

// ---------------- launch ----------------

extern "C" void kernel_launch(void* const* d_in, const int* in_sizes, int n_in,
                              void* d_out, int out_size, void* d_ws, size_t ws_size,
                              hipStream_t stream) {
  const float* x = (const float*)d_in[0];
  const int* ei = (const int*)d_in[1];
  const float* Ws = (const float*)d_in[2];
  const float* bs = (const float*)d_in[3];
  const float* lnw = (const float*)d_in[4];
  const float* lnb = (const float*)d_in[5];
  float* out = (float*)d_out;

  const int N = in_sizes[0] / DD;
  const int E = in_sizes[1] / 2;
  const int L = in_sizes[2] / (DD * DD);
  const int* srcp = ei;
  const int* dstp = ei + E;

  char* p = (char*)d_ws;
  size_t ofs = 0;
  auto carve = [&](size_t bytes) -> void* {
    void* r = p + ofs;
    ofs = (ofs + bytes + 255) & ~(size_t)255;
    return r;
  };
  int* cnt = (int*)carve((size_t)N * 4);
  int* offv = (int*)carve((size_t)(N + 1) * 4);
  int* cursor = (int*)carve((size_t)N * 4);
  float* dinv = (float*)carve((size_t)N * 4);
  int* bsums = (int*)carve(4096);
  double* sums = (double*)carve(16 * sizeof(double));
  float* stats = (float*)carve(16 * sizeof(float));
  int2* csr = (int2*)carve((size_t)E * 8);
  float* bufA = (float*)carve((size_t)N * DD * 4);
  float* bufB = (float*)carve((size_t)N * DD * 4);

  hipMemsetAsync(cnt, 0, (size_t)N * 4, stream);
  hipMemsetAsync(sums, 0, 16 * sizeof(double), stream);

  int gE = (E + 255) / 256;
  int gN = (N + 255) / 256;
  count_deg_k<<<gE, 256, 0, stream>>>(dstp, cnt, E);
  dinv_k<<<gN, 256, 0, stream>>>(cnt, dinv, N);
  int nb = (N + 1023) / 1024;
  scan_a_k<<<nb, 256, 0, stream>>>(cnt, offv, bsums, N);
  scan_b_k<<<1, 64, 0, stream>>>(bsums, nb);
  scan_c_k<<<(N + 256) / 256, 256, 0, stream>>>(offv, cursor, bsums, N, E);
  fill_csr_k<<<gE, 256, 0, stream>>>(srcp, dstp, dinv, cursor, csr, E);

  int gGemm = (N + 63) / 64;
  int gAgg = (N * DD + 255) / 256;  // one wave per node
  for (int l = 0; l < L; ++l) {
    const float* in = (l == 0) ? x : bufB;
    const float* plnw = (l == 0) ? lnw : lnw + (l - 1) * DD;
    const float* plnb = (l == 0) ? lnb : lnb + (l - 1) * DD;
    const float* pst = (l == 0) ? stats : stats + (l - 1) * 2;
    gemm_ln_k<<<gGemm, 256, 0, stream>>>(in, Ws + (size_t)l * DD * DD, bufA, plnw, plnb, pst,
                                         (l > 0) ? 1 : 0, N);
    float* aggout = (l == L - 1) ? out : bufB;
    agg_k<<<gAgg, 256, 0, stream>>>(bufA, offv, csr, dinv, bs + (size_t)l * DD, aggout,
                                    sums + l * 2, N);
    finalize_k<<<1, 1, 0, stream>>>(sums + l * 2, stats + l * 2, N * DD);
  }
  norm_relu_k<<<(N * (DD / 4) + 255) / 256, 256, 0, stream>>>(out, lnw + (size_t)(L - 1) * DD,
                                                              lnb + (size_t)(L - 1) * DD,
                                                              stats + (L - 1) * 2, N * (DD / 4));
}

// Round 2
// 2729.491 us; speedup vs baseline: 1.0148x; 1.0148x over previous
//
#include <hip/hip_runtime.h>

#define DD 64

// ---------------- degree / CSR build ----------------

__global__ __launch_bounds__(256) void count_deg_k(const int* __restrict__ dst, int* __restrict__ cnt, int E) {
  int e = blockIdx.x * 256 + threadIdx.x;
  if (e < E) atomicAdd(&cnt[dst[e]], 1);
}

__global__ __launch_bounds__(256) void dinv_k(const int* __restrict__ cnt, float* __restrict__ dinv, int n) {
  int i = blockIdx.x * 256 + threadIdx.x;
  if (i < n) dinv[i] = rsqrtf((float)cnt[i] + 1.0f);
}

// block scans 1024 elements (256 thr x 4); writes local-exclusive prefix + block total
__global__ __launch_bounds__(256) void scan_a_k(const int* __restrict__ cnt, int* __restrict__ out,
                                                int* __restrict__ bsums, int n) {
  __shared__ int ts[256];
  int t = threadIdx.x;
  int base = blockIdx.x * 1024 + t * 4;
  int c0 = 0, c1 = 0, c2 = 0, c3 = 0;
  if (base + 3 < n) {
    int4 v = *(const int4*)(cnt + base);
    c0 = v.x; c1 = v.y; c2 = v.z; c3 = v.w;
  } else {
    if (base + 0 < n) c0 = cnt[base + 0];
    if (base + 1 < n) c1 = cnt[base + 1];
    if (base + 2 < n) c2 = cnt[base + 2];
  }
  int s = c0 + c1 + c2 + c3;
  ts[t] = s;
  __syncthreads();
  for (int o = 1; o < 256; o <<= 1) {
    int v = 0;
    if (t >= o) v = ts[t - o];
    __syncthreads();
    ts[t] += v;
    __syncthreads();
  }
  int excl = ts[t] - s;
  if (base + 0 < n) out[base + 0] = excl;
  if (base + 1 < n) out[base + 1] = excl + c0;
  if (base + 2 < n) out[base + 2] = excl + c0 + c1;
  if (base + 3 < n) out[base + 3] = excl + c0 + c1 + c2;
  if (t == 255) bsums[blockIdx.x] = ts[255];
}

__global__ void scan_b_k(int* bsums, int nb) {
  if (threadIdx.x == 0 && blockIdx.x == 0) {
    int run = 0;
    for (int i = 0; i < nb; ++i) { int v = bsums[i]; bsums[i] = run; run += v; }
  }
}

__global__ __launch_bounds__(256) void scan_c_k(int* __restrict__ off, int* __restrict__ cursor,
                                                const int* __restrict__ bsums, int n, int E) {
  int i = blockIdx.x * 256 + threadIdx.x;
  if (i < n) {
    int v = off[i] + bsums[i >> 10];
    off[i] = v;
    cursor[i] = v;
  } else if (i == n) {
    off[n] = E;
  }
}

__global__ __launch_bounds__(256) void fill_csr_k(const int* __restrict__ src, const int* __restrict__ dst,
                                                  const float* __restrict__ dinv, int* __restrict__ cursor,
                                                  int2* __restrict__ csr, int E) {
  int e = blockIdx.x * 256 + threadIdx.x;
  if (e < E) {
    int s = src[e], d = dst[e];
    int pos = atomicAdd(&cursor[d], 1);
    float w = dinv[s] * dinv[d];
    csr[pos] = make_int2(s, __float_as_int(w));
  }
}

// ---------------- per-layer kernels ----------------

// out[row] = act(in[row]) @ W ; act = identity (layer 0) or relu(ln(.)) of previous layer
__global__ __launch_bounds__(256) void gemm_ln_k(const float* __restrict__ in, const float* __restrict__ W,
                                                 float* __restrict__ out, const float* __restrict__ lnw,
                                                 const float* __restrict__ lnb, const float* __restrict__ stats,
                                                 int applyLn, int n) {
  __shared__ float Wl[64 * 64];
  __shared__ float Al[64 * 68];  // stride 68: float4-aligned, 2-way bank alias only (free)
  int t = threadIdx.x;
#pragma unroll
  for (int i = 0; i < 4; ++i)
    ((float4*)Wl)[t + i * 256] = ((const float4*)W)[t + i * 256];
  float mean = 0.f, rstd = 1.f;
  if (applyLn) { mean = stats[0]; rstd = stats[1]; }
  int row0 = blockIdx.x * 64;
#pragma unroll
  for (int i = 0; i < 4; ++i) {
    int q = t + i * 256;         // float4 index within 64x64 tile
    int r = q >> 4, c4 = q & 15;
    int gr = row0 + r;
    float4 v = make_float4(0.f, 0.f, 0.f, 0.f);
    if (gr < n) v = ((const float4*)in)[(size_t)gr * 16 + c4];
    if (applyLn) {
      int c = c4 * 4;
      v.x = fmaxf(fmaf((v.x - mean) * rstd, lnw[c + 0], lnb[c + 0]), 0.f);
      v.y = fmaxf(fmaf((v.y - mean) * rstd, lnw[c + 1], lnb[c + 1]), 0.f);
      v.z = fmaxf(fmaf((v.z - mean) * rstd, lnw[c + 2], lnb[c + 2]), 0.f);
      v.w = fmaxf(fmaf((v.w - mean) * rstd, lnw[c + 3], lnb[c + 3]), 0.f);
    }
    *(float4*)&Al[r * 68 + c4 * 4] = v;
  }
  __syncthreads();
  int r = t >> 2, cb = (t & 3) * 16;
  float acc[16];
#pragma unroll
  for (int j = 0; j < 16; ++j) acc[j] = 0.f;
  for (int k = 0; k < 64; ++k) {
    float a = Al[r * 68 + k];
#pragma unroll
    for (int j = 0; j < 16; ++j) acc[j] = fmaf(a, Wl[k * 64 + cb + j], acc[j]);
  }
  int gr = row0 + r;
  if (gr < n) {
    float4* op = (float4*)&out[(size_t)gr * 64 + cb];
    op[0] = make_float4(acc[0], acc[1], acc[2], acc[3]);
    op[1] = make_float4(acc[4], acc[5], acc[6], acc[7]);
    op[2] = make_float4(acc[8], acc[9], acc[10], acc[11]);
    op[3] = make_float4(acc[12], acc[13], acc[14], acc[15]);
  }
}

// wave-per-node CSR gather + bias + self-loop; accumulates global sum/sumsq.
// Edge loop batched 16-deep: 16 independent csr loads, then 16 independent
// row gathers in flight per wave (MLP=16 vs 1 in the serial version).
#define CHUNK 16
__global__ __launch_bounds__(256) void agg_k(const float* __restrict__ hw, const int* __restrict__ off,
                                             const int2* __restrict__ csr, const float* __restrict__ dinv,
                                             const float* __restrict__ bias, float* __restrict__ out,
                                             double* __restrict__ sums, int n) {
  int wid = (int)((blockIdx.x * 256 + threadIdx.x) >> 6);
  int lane = threadIdx.x & 63;
  float s1 = 0.f, s2 = 0.f;
  if (wid < n) {
    float di = dinv[wid];
    float acc = fmaf(di * di, hw[(size_t)wid * 64 + lane], bias[lane]);
    int e0 = off[wid], e1 = off[wid + 1];
    for (int base = e0; base < e1; base += CHUNK) {
      int2 ew[CHUNK];
#pragma unroll
      for (int j = 0; j < CHUNK; ++j) {
        int idx = base + j;
        ew[j] = csr[idx < e1 ? idx : e1 - 1];
      }
      float v[CHUNK];
#pragma unroll
      for (int j = 0; j < CHUNK; ++j) v[j] = hw[(size_t)ew[j].x * 64 + lane];
#pragma unroll
      for (int j = 0; j < CHUNK; ++j) {
        float w = (base + j < e1) ? __int_as_float(ew[j].y) : 0.f;
        acc = fmaf(w, v[j], acc);
      }
    }
    out[(size_t)wid * 64 + lane] = acc;
    s1 = acc;
    s2 = acc * acc;
  }
#pragma unroll
  for (int o = 32; o > 0; o >>= 1) {
    s1 += __shfl_down(s1, o);
    s2 += __shfl_down(s2, o);
  }
  __shared__ float red1[4], red2[4];
  int w = threadIdx.x >> 6;
  if (lane == 0) { red1[w] = s1; red2[w] = s2; }
  __syncthreads();
  if (threadIdx.x == 0) {
    double a = (double)red1[0] + (double)red1[1] + (double)red1[2] + (double)red1[3];
    double b = (double)red2[0] + (double)red2[1] + (double)red2[2] + (double)red2[3];
    atomicAdd(&sums[0], a);
    atomicAdd(&sums[1], b);
  }
}

__global__ void finalize_k(const double* __restrict__ sums, float* __restrict__ stats, int M) {
  double mean = sums[0] / M;
  double var = sums[1] / M - mean * mean;
  stats[0] = (float)mean;
  stats[1] = (float)rsqrt(var + 1e-5);
}

// final layer: in-place ln+relu on d_out
__global__ __launch_bounds__(256) void norm_relu_k(float* __restrict__ io, const float* __restrict__ lnw,
                                                   const float* __restrict__ lnb, const float* __restrict__ stats,
                                                   int n4) {
  int i = blockIdx.x * 256 + threadIdx.x;
  if (i >= n4) return;
  float mean = stats[0], rstd = stats[1];
  float4 v = ((float4*)io)[i];
  int c = (i & 15) * 4;
  v.x = fmaxf(fmaf((v.x - mean) * rstd, lnw[c + 0], lnb[c + 0]), 0.f);
  v.y = fmaxf(fmaf((v.y - mean) * rstd, lnw[c + 1], lnb[c + 1]), 0.f);
  v.z = fmaxf(fmaf((v.z - mean) * rstd, lnw[c + 2], lnb[c + 2]), 0.f);
  v.w = fmaxf(fmaf((v.w - mean) * rstd, lnw[c + 3], lnb[c + 3]), 0.f);
  ((float4*)io)[i] = v;
}

// ---------------- launch ----------------

extern "C" void kernel_launch(void* const* d_in, const int* in_sizes, int n_in,
                              void* d_out, int out_size, void* d_ws, size_t ws_size,
                              hipStream_t stream) {
  const float* x = (const float*)d_in[0];
  const int* ei = (const int*)d_in[1];
  const float* Ws = (const float*)d_in[2];
  const float* bs = (const float*)d_in[3];
  const float* lnw = (const float*)d_in[4];
  const float* lnb = (const float*)d_in[5];
  float* out = (float*)d_out;

  const int N = in_sizes[0] / DD;
  const int E = in_sizes[1] / 2;
  const int L = in_sizes[2] / (DD * DD);
  const int* srcp = ei;
  const int* dstp = ei + E;

  char* p = (char*)d_ws;
  size_t ofs = 0;
  auto carve = [&](size_t bytes) -> void* {
    void* r = p + ofs;
    ofs = (ofs + bytes + 255) & ~(size_t)255;
    return r;
  };
  int* cnt = (int*)carve((size_t)N * 4);
  int* offv = (int*)carve((size_t)(N + 1) * 4);
  int* cursor = (int*)carve((size_t)N * 4);
  float* dinv = (float*)carve((size_t)N * 4);
  int* bsums = (int*)carve(4096);
  double* sums = (double*)carve(16 * sizeof(double));
  float* stats = (float*)carve(16 * sizeof(float));
  int2* csr = (int2*)carve((size_t)E * 8);
  float* bufA = (float*)carve((size_t)N * DD * 4);
  float* bufB = (float*)carve((size_t)N * DD * 4);

  hipMemsetAsync(cnt, 0, (size_t)N * 4, stream);
  hipMemsetAsync(sums, 0, 16 * sizeof(double), stream);

  int gE = (E + 255) / 256;
  int gN = (N + 255) / 256;
  count_deg_k<<<gE, 256, 0, stream>>>(dstp, cnt, E);
  dinv_k<<<gN, 256, 0, stream>>>(cnt, dinv, N);
  int nb = (N + 1023) / 1024;
  scan_a_k<<<nb, 256, 0, stream>>>(cnt, offv, bsums, N);
  scan_b_k<<<1, 64, 0, stream>>>(bsums, nb);
  scan_c_k<<<(N + 256) / 256, 256, 0, stream>>>(offv, cursor, bsums, N, E);
  fill_csr_k<<<gE, 256, 0, stream>>>(srcp, dstp, dinv, cursor, csr, E);

  int gGemm = (N + 63) / 64;
  int gAgg = (N * DD + 255) / 256;  // one wave per node
  for (int l = 0; l < L; ++l) {
    const float* in = (l == 0) ? x : bufB;
    const float* plnw = (l == 0) ? lnw : lnw + (l - 1) * DD;
    const float* plnb = (l == 0) ? lnb : lnb + (l - 1) * DD;
    const float* pst = (l == 0) ? stats : stats + (l - 1) * 2;
    gemm_ln_k<<<gGemm, 256, 0, stream>>>(in, Ws + (size_t)l * DD * DD, bufA, plnw, plnb, pst,
                                         (l > 0) ? 1 : 0, N);
    float* aggout = (l == L - 1) ? out : bufB;
    agg_k<<<gAgg, 256, 0, stream>>>(bufA, offv, csr, dinv, bs + (size_t)l * DD, aggout,
                                    sums + l * 2, N);
    finalize_k<<<1, 1, 0, stream>>>(sums + l * 2, stats + l * 2, N * DD);
  }
  norm_relu_k<<<(N * (DD / 4) + 255) / 256, 256, 0, stream>>>(out, lnw + (size_t)(L - 1) * DD,
                                                              lnb + (size_t)(L - 1) * DD,
                                                              stats + (L - 1) * 2, N * (DD / 4));
}

// Round 3
// 2715.208 us; speedup vs baseline: 1.0201x; 1.0053x over previous
//
#include <hip/hip_runtime.h>

#define DD 64

// ---------------- degree / CSR build ----------------

__global__ __launch_bounds__(256) void count_deg_k(const int* __restrict__ dst, int* __restrict__ cnt, int E) {
  int e = blockIdx.x * 256 + threadIdx.x;
  if (e < E) atomicAdd(&cnt[dst[e]], 1);
}

__global__ __launch_bounds__(256) void dinv_k(const int* __restrict__ cnt, float* __restrict__ dinv, int n) {
  int i = blockIdx.x * 256 + threadIdx.x;
  if (i < n) dinv[i] = rsqrtf((float)cnt[i] + 1.0f);
}

// block scans 1024 elements (256 thr x 4); writes local-exclusive prefix + block total
__global__ __launch_bounds__(256) void scan_a_k(const int* __restrict__ cnt, int* __restrict__ out,
                                                int* __restrict__ bsums, int n) {
  __shared__ int ts[256];
  int t = threadIdx.x;
  int base = blockIdx.x * 1024 + t * 4;
  int c0 = 0, c1 = 0, c2 = 0, c3 = 0;
  if (base + 3 < n) {
    int4 v = *(const int4*)(cnt + base);
    c0 = v.x; c1 = v.y; c2 = v.z; c3 = v.w;
  } else {
    if (base + 0 < n) c0 = cnt[base + 0];
    if (base + 1 < n) c1 = cnt[base + 1];
    if (base + 2 < n) c2 = cnt[base + 2];
  }
  int s = c0 + c1 + c2 + c3;
  ts[t] = s;
  __syncthreads();
  for (int o = 1; o < 256; o <<= 1) {
    int v = 0;
    if (t >= o) v = ts[t - o];
    __syncthreads();
    ts[t] += v;
    __syncthreads();
  }
  int excl = ts[t] - s;
  if (base + 0 < n) out[base + 0] = excl;
  if (base + 1 < n) out[base + 1] = excl + c0;
  if (base + 2 < n) out[base + 2] = excl + c0 + c1;
  if (base + 3 < n) out[base + 3] = excl + c0 + c1 + c2;
  if (t == 255) bsums[blockIdx.x] = ts[255];
}

__global__ void scan_b_k(int* bsums, int nb) {
  if (threadIdx.x == 0 && blockIdx.x == 0) {
    int run = 0;
    for (int i = 0; i < nb; ++i) { int v = bsums[i]; bsums[i] = run; run += v; }
  }
}

__global__ __launch_bounds__(256) void scan_c_k(int* __restrict__ off, int* __restrict__ cursor,
                                                const int* __restrict__ bsums, int n, int E) {
  int i = blockIdx.x * 256 + threadIdx.x;
  if (i < n) {
    int v = off[i] + bsums[i >> 10];
    off[i] = v;
    cursor[i] = v;
  } else if (i == n) {
    off[n] = E;
  }
}

__global__ __launch_bounds__(256) void fill_csr_k(const int* __restrict__ src, const int* __restrict__ dst,
                                                  const float* __restrict__ dinv, int* __restrict__ cursor,
                                                  int2* __restrict__ csr, int E) {
  int e = blockIdx.x * 256 + threadIdx.x;
  if (e < E) {
    int s = src[e], d = dst[e];
    int pos = atomicAdd(&cursor[d], 1);
    float w = dinv[s] * dinv[d];
    csr[pos] = make_int2(s, __float_as_int(w));
  }
}

// ---------------- per-layer kernels ----------------

// out[row] = act(in[row]) @ W ; act = identity (layer 0) or relu(ln(.)) of previous layer
__global__ __launch_bounds__(256) void gemm_ln_k(const float* __restrict__ in, const float* __restrict__ W,
                                                 float* __restrict__ out, const float* __restrict__ lnw,
                                                 const float* __restrict__ lnb, const float* __restrict__ stats,
                                                 int applyLn, int n) {
  __shared__ float Wl[64 * 64];
  __shared__ float Al[64 * 68];
  int t = threadIdx.x;
#pragma unroll
  for (int i = 0; i < 4; ++i)
    ((float4*)Wl)[t + i * 256] = ((const float4*)W)[t + i * 256];
  float mean = 0.f, rstd = 1.f;
  if (applyLn) { mean = stats[0]; rstd = stats[1]; }
  int row0 = blockIdx.x * 64;
#pragma unroll
  for (int i = 0; i < 4; ++i) {
    int q = t + i * 256;
    int r = q >> 4, c4 = q & 15;
    int gr = row0 + r;
    float4 v = make_float4(0.f, 0.f, 0.f, 0.f);
    if (gr < n) v = ((const float4*)in)[(size_t)gr * 16 + c4];
    if (applyLn) {
      int c = c4 * 4;
      v.x = fmaxf(fmaf((v.x - mean) * rstd, lnw[c + 0], lnb[c + 0]), 0.f);
      v.y = fmaxf(fmaf((v.y - mean) * rstd, lnw[c + 1], lnb[c + 1]), 0.f);
      v.z = fmaxf(fmaf((v.z - mean) * rstd, lnw[c + 2], lnb[c + 2]), 0.f);
      v.w = fmaxf(fmaf((v.w - mean) * rstd, lnw[c + 3], lnb[c + 3]), 0.f);
    }
    *(float4*)&Al[r * 68 + c4 * 4] = v;
  }
  __syncthreads();
  int r = t >> 2, cb = (t & 3) * 16;
  float acc[16];
#pragma unroll
  for (int j = 0; j < 16; ++j) acc[j] = 0.f;
  for (int k = 0; k < 64; ++k) {
    float a = Al[r * 68 + k];
#pragma unroll
    for (int j = 0; j < 16; ++j) acc[j] = fmaf(a, Wl[k * 64 + cb + j], acc[j]);
  }
  int gr = row0 + r;
  if (gr < n) {
    float4* op = (float4*)&out[(size_t)gr * 64 + cb];
    op[0] = make_float4(acc[0], acc[1], acc[2], acc[3]);
    op[1] = make_float4(acc[4], acc[5], acc[6], acc[7]);
    op[2] = make_float4(acc[8], acc[9], acc[10], acc[11]);
    op[3] = make_float4(acc[12], acc[13], acc[14], acc[15]);
  }
}

// wave-per-node; quarter-wave (16 lanes) per edge, float4 per lane.
// 16 edges per iteration = 4 independent float4 gathers per lane in flight
// (4 VGPR per in-flight item keeps compiler from re-serializing).
__global__ __launch_bounds__(256) void agg_k(const float4* __restrict__ hw4, const int* __restrict__ off,
                                             const int2* __restrict__ csr, const float* __restrict__ dinv,
                                             const float4* __restrict__ bias4, float4* __restrict__ out4,
                                             double* __restrict__ sums, int n) {
  int wid = (int)((blockIdx.x * 256 + threadIdx.x) >> 6);
  int lane = threadIdx.x & 63;
  int g = lane >> 4, q = lane & 15;
  float4 acc = make_float4(0.f, 0.f, 0.f, 0.f);
  float s1 = 0.f, s2 = 0.f;
  if (wid < n) {
    if (g == 0) {
      float di = dinv[wid];
      float w = di * di;
      float4 h = hw4[(size_t)wid * 16 + q];
      float4 b = bias4[q];
      acc.x = fmaf(w, h.x, b.x);
      acc.y = fmaf(w, h.y, b.y);
      acc.z = fmaf(w, h.z, b.z);
      acc.w = fmaf(w, h.w, b.w);
    }
    int e0 = off[wid], e1 = off[wid + 1];
    for (int base = e0; base < e1; base += 16) {
      int eb = base + g * 4;  // this quarter-wave's 4 edges
      int2 c0 = csr[eb + 0];
      int2 c1 = csr[eb + 1];
      int2 c2 = csr[eb + 2];
      int2 c3 = csr[eb + 3];
      int i0 = (eb + 0 < e1) ? c0.x : 0;
      int i1 = (eb + 1 < e1) ? c1.x : 0;
      int i2 = (eb + 2 < e1) ? c2.x : 0;
      int i3 = (eb + 3 < e1) ? c3.x : 0;
      float w0 = (eb + 0 < e1) ? __int_as_float(c0.y) : 0.f;
      float w1 = (eb + 1 < e1) ? __int_as_float(c1.y) : 0.f;
      float w2 = (eb + 2 < e1) ? __int_as_float(c2.y) : 0.f;
      float w3 = (eb + 3 < e1) ? __int_as_float(c3.y) : 0.f;
      float4 v0 = hw4[(size_t)i0 * 16 + q];
      float4 v1 = hw4[(size_t)i1 * 16 + q];
      float4 v2 = hw4[(size_t)i2 * 16 + q];
      float4 v3 = hw4[(size_t)i3 * 16 + q];
      acc.x = fmaf(w0, v0.x, acc.x); acc.y = fmaf(w0, v0.y, acc.y);
      acc.z = fmaf(w0, v0.z, acc.z); acc.w = fmaf(w0, v0.w, acc.w);
      acc.x = fmaf(w1, v1.x, acc.x); acc.y = fmaf(w1, v1.y, acc.y);
      acc.z = fmaf(w1, v1.z, acc.z); acc.w = fmaf(w1, v1.w, acc.w);
      acc.x = fmaf(w2, v2.x, acc.x); acc.y = fmaf(w2, v2.y, acc.y);
      acc.z = fmaf(w2, v2.z, acc.z); acc.w = fmaf(w2, v2.w, acc.w);
      acc.x = fmaf(w3, v3.x, acc.x); acc.y = fmaf(w3, v3.y, acc.y);
      acc.z = fmaf(w3, v3.z, acc.z); acc.w = fmaf(w3, v3.w, acc.w);
    }
    // sum the 4 quarter-wave partials (lanes q, q+16, q+32, q+48)
#pragma unroll
    for (int o = 16; o <= 32; o <<= 1) {
      acc.x += __shfl_xor(acc.x, o);
      acc.y += __shfl_xor(acc.y, o);
      acc.z += __shfl_xor(acc.z, o);
      acc.w += __shfl_xor(acc.w, o);
    }
    if (g == 0) {
      out4[(size_t)wid * 16 + q] = acc;
      s1 = acc.x + acc.y + acc.z + acc.w;
      s2 = acc.x * acc.x + acc.y * acc.y + acc.z * acc.z + acc.w * acc.w;
    }
  }
  // full-wave reduce (only g==0 lanes contributed)
#pragma unroll
  for (int o = 1; o <= 32; o <<= 1) {
    s1 += __shfl_xor(s1, o);
    s2 += __shfl_xor(s2, o);
  }
  __shared__ float red1[4], red2[4];
  int w = threadIdx.x >> 6;
  if (lane == 0) { red1[w] = s1; red2[w] = s2; }
  __syncthreads();
  if (threadIdx.x == 0) {
    double a = (double)red1[0] + (double)red1[1] + (double)red1[2] + (double)red1[3];
    double b = (double)red2[0] + (double)red2[1] + (double)red2[2] + (double)red2[3];
    atomicAdd(&sums[0], a);
    atomicAdd(&sums[1], b);
  }
}

__global__ void finalize_k(const double* __restrict__ sums, float* __restrict__ stats, int M) {
  double mean = sums[0] / M;
  double var = sums[1] / M - mean * mean;
  stats[0] = (float)mean;
  stats[1] = (float)rsqrt(var + 1e-5);
}

// final layer: in-place ln+relu on d_out
__global__ __launch_bounds__(256) void norm_relu_k(float* __restrict__ io, const float* __restrict__ lnw,
                                                   const float* __restrict__ lnb, const float* __restrict__ stats,
                                                   int n4) {
  int i = blockIdx.x * 256 + threadIdx.x;
  if (i >= n4) return;
  float mean = stats[0], rstd = stats[1];
  float4 v = ((float4*)io)[i];
  int c = (i & 15) * 4;
  v.x = fmaxf(fmaf((v.x - mean) * rstd, lnw[c + 0], lnb[c + 0]), 0.f);
  v.y = fmaxf(fmaf((v.y - mean) * rstd, lnw[c + 1], lnb[c + 1]), 0.f);
  v.z = fmaxf(fmaf((v.z - mean) * rstd, lnw[c + 2], lnb[c + 2]), 0.f);
  v.w = fmaxf(fmaf((v.w - mean) * rstd, lnw[c + 3], lnb[c + 3]), 0.f);
  ((float4*)io)[i] = v;
}

// ---------------- launch ----------------

extern "C" void kernel_launch(void* const* d_in, const int* in_sizes, int n_in,
                              void* d_out, int out_size, void* d_ws, size_t ws_size,
                              hipStream_t stream) {
  const float* x = (const float*)d_in[0];
  const int* ei = (const int*)d_in[1];
  const float* Ws = (const float*)d_in[2];
  const float* bs = (const float*)d_in[3];
  const float* lnw = (const float*)d_in[4];
  const float* lnb = (const float*)d_in[5];
  float* out = (float*)d_out;

  const int N = in_sizes[0] / DD;
  const int E = in_sizes[1] / 2;
  const int L = in_sizes[2] / (DD * DD);
  const int* srcp = ei;
  const int* dstp = ei + E;

  char* p = (char*)d_ws;
  size_t ofs = 0;
  auto carve = [&](size_t bytes) -> void* {
    void* r = p + ofs;
    ofs = (ofs + bytes + 255) & ~(size_t)255;
    return r;
  };
  int* cnt = (int*)carve((size_t)N * 4);
  int* offv = (int*)carve((size_t)(N + 1) * 4);
  int* cursor = (int*)carve((size_t)N * 4);
  float* dinv = (float*)carve((size_t)N * 4);
  int* bsums = (int*)carve(4096);
  double* sums = (double*)carve(16 * sizeof(double));
  float* stats = (float*)carve(16 * sizeof(float));
  int2* csr = (int2*)carve((size_t)(E + 16) * 8);  // +16: unrolled tail over-read
  float* bufA = (float*)carve((size_t)N * DD * 4);
  float* bufB = (float*)carve((size_t)N * DD * 4);

  hipMemsetAsync(cnt, 0, (size_t)N * 4, stream);
  hipMemsetAsync(sums, 0, 16 * sizeof(double), stream);

  int gE = (E + 255) / 256;
  int gN = (N + 255) / 256;
  count_deg_k<<<gE, 256, 0, stream>>>(dstp, cnt, E);
  dinv_k<<<gN, 256, 0, stream>>>(cnt, dinv, N);
  int nb = (N + 1023) / 1024;
  scan_a_k<<<nb, 256, 0, stream>>>(cnt, offv, bsums, N);
  scan_b_k<<<1, 64, 0, stream>>>(bsums, nb);
  scan_c_k<<<(N + 256) / 256, 256, 0, stream>>>(offv, cursor, bsums, N, E);
  fill_csr_k<<<gE, 256, 0, stream>>>(srcp, dstp, dinv, cursor, csr, E);

  int gGemm = (N + 63) / 64;
  int gAgg = (N * DD + 255) / 256;  // one wave per node
  for (int l = 0; l < L; ++l) {
    const float* in = (l == 0) ? x : bufB;
    const float* plnw = (l == 0) ? lnw : lnw + (l - 1) * DD;
    const float* plnb = (l == 0) ? lnb : lnb + (l - 1) * DD;
    const float* pst = (l == 0) ? stats : stats + (l - 1) * 2;
    gemm_ln_k<<<gGemm, 256, 0, stream>>>(in, Ws + (size_t)l * DD * DD, bufA, plnw, plnb, pst,
                                         (l > 0) ? 1 : 0, N);
    float* aggout = (l == L - 1) ? out : bufB;
    agg_k<<<gAgg, 256, 0, stream>>>((const float4*)bufA, offv, csr, dinv,
                                    (const float4*)(bs + (size_t)l * DD), (float4*)aggout,
                                    sums + l * 2, N);
    finalize_k<<<1, 1, 0, stream>>>(sums + l * 2, stats + l * 2, N * DD);
  }
  norm_relu_k<<<(N * (DD / 4) + 255) / 256, 256, 0, stream>>>(out, lnw + (size_t)(L - 1) * DD,
                                                              lnb + (size_t)(L - 1) * DD,
                                                              stats + (L - 1) * 2, N * (DD / 4));
}

// Round 4
// 525.908 us; speedup vs baseline: 5.2668x; 5.1629x over previous
//
#include <hip/hip_runtime.h>

#define DD 64
#define NBUCK 256
#define BSTRIDE 32  // doubles; 256B spacing -> distinct L2 lines/channels

// ---------------- degree / CSR build ----------------

__global__ __launch_bounds__(256) void count_deg_k(const int* __restrict__ dst, int* __restrict__ cnt, int E) {
  int e = blockIdx.x * 256 + threadIdx.x;
  if (e < E) atomicAdd(&cnt[dst[e]], 1);
}

__global__ __launch_bounds__(256) void dinv_k(const int* __restrict__ cnt, float* __restrict__ dinv, int n) {
  int i = blockIdx.x * 256 + threadIdx.x;
  if (i < n) dinv[i] = rsqrtf((float)cnt[i] + 1.0f);
}

// block scans 1024 elements (256 thr x 4); writes local-exclusive prefix + block total
__global__ __launch_bounds__(256) void scan_a_k(const int* __restrict__ cnt, int* __restrict__ out,
                                                int* __restrict__ bsums, int n) {
  __shared__ int ts[256];
  int t = threadIdx.x;
  int base = blockIdx.x * 1024 + t * 4;
  int c0 = 0, c1 = 0, c2 = 0, c3 = 0;
  if (base + 3 < n) {
    int4 v = *(const int4*)(cnt + base);
    c0 = v.x; c1 = v.y; c2 = v.z; c3 = v.w;
  } else {
    if (base + 0 < n) c0 = cnt[base + 0];
    if (base + 1 < n) c1 = cnt[base + 1];
    if (base + 2 < n) c2 = cnt[base + 2];
  }
  int s = c0 + c1 + c2 + c3;
  ts[t] = s;
  __syncthreads();
  for (int o = 1; o < 256; o <<= 1) {
    int v = 0;
    if (t >= o) v = ts[t - o];
    __syncthreads();
    ts[t] += v;
    __syncthreads();
  }
  int excl = ts[t] - s;
  if (base + 0 < n) out[base + 0] = excl;
  if (base + 1 < n) out[base + 1] = excl + c0;
  if (base + 2 < n) out[base + 2] = excl + c0 + c1;
  if (base + 3 < n) out[base + 3] = excl + c0 + c1 + c2;
  if (t == 255) bsums[blockIdx.x] = ts[255];
}

__global__ void scan_b_k(int* bsums, int nb) {
  if (threadIdx.x == 0 && blockIdx.x == 0) {
    int run = 0;
    for (int i = 0; i < nb; ++i) { int v = bsums[i]; bsums[i] = run; run += v; }
  }
}

__global__ __launch_bounds__(256) void scan_c_k(int* __restrict__ off, int* __restrict__ cursor,
                                                const int* __restrict__ bsums, int n, int E) {
  int i = blockIdx.x * 256 + threadIdx.x;
  if (i < n) {
    int v = off[i] + bsums[i >> 10];
    off[i] = v;
    cursor[i] = v;
  } else if (i == n) {
    off[n] = E;
  }
}

__global__ __launch_bounds__(256) void fill_csr_k(const int* __restrict__ src, const int* __restrict__ dst,
                                                  const float* __restrict__ dinv, int* __restrict__ cursor,
                                                  int2* __restrict__ csr, int E) {
  int e = blockIdx.x * 256 + threadIdx.x;
  if (e < E) {
    int s = src[e], d = dst[e];
    int pos = atomicAdd(&cursor[d], 1);
    float w = dinv[s] * dinv[d];
    csr[pos] = make_int2(s, __float_as_int(w));
  }
}

// ---------------- per-layer kernels ----------------

// out[row] = act(in[row]) @ W ; act = identity (layer 0) or relu(ln(.)) of previous layer
__global__ __launch_bounds__(256) void gemm_ln_k(const float* __restrict__ in, const float* __restrict__ W,
                                                 float* __restrict__ out, const float* __restrict__ lnw,
                                                 const float* __restrict__ lnb, const float* __restrict__ stats,
                                                 int applyLn, int n) {
  __shared__ float Wl[64 * 64];
  __shared__ float Al[64 * 68];
  int t = threadIdx.x;
#pragma unroll
  for (int i = 0; i < 4; ++i)
    ((float4*)Wl)[t + i * 256] = ((const float4*)W)[t + i * 256];
  float mean = 0.f, rstd = 1.f;
  if (applyLn) { mean = stats[0]; rstd = stats[1]; }
  int row0 = blockIdx.x * 64;
#pragma unroll
  for (int i = 0; i < 4; ++i) {
    int q = t + i * 256;
    int r = q >> 4, c4 = q & 15;
    int gr = row0 + r;
    float4 v = make_float4(0.f, 0.f, 0.f, 0.f);
    if (gr < n) v = ((const float4*)in)[(size_t)gr * 16 + c4];
    if (applyLn) {
      int c = c4 * 4;
      v.x = fmaxf(fmaf((v.x - mean) * rstd, lnw[c + 0], lnb[c + 0]), 0.f);
      v.y = fmaxf(fmaf((v.y - mean) * rstd, lnw[c + 1], lnb[c + 1]), 0.f);
      v.z = fmaxf(fmaf((v.z - mean) * rstd, lnw[c + 2], lnb[c + 2]), 0.f);
      v.w = fmaxf(fmaf((v.w - mean) * rstd, lnw[c + 3], lnb[c + 3]), 0.f);
    }
    *(float4*)&Al[r * 68 + c4 * 4] = v;
  }
  __syncthreads();
  int r = t >> 2, cb = (t & 3) * 16;
  float acc[16];
#pragma unroll
  for (int j = 0; j < 16; ++j) acc[j] = 0.f;
  for (int k = 0; k < 64; ++k) {
    float a = Al[r * 68 + k];
#pragma unroll
    for (int j = 0; j < 16; ++j) acc[j] = fmaf(a, Wl[k * 64 + cb + j], acc[j]);
  }
  int gr = row0 + r;
  if (gr < n) {
    float4* op = (float4*)&out[(size_t)gr * 64 + cb];
    op[0] = make_float4(acc[0], acc[1], acc[2], acc[3]);
    op[1] = make_float4(acc[4], acc[5], acc[6], acc[7]);
    op[2] = make_float4(acc[8], acc[9], acc[10], acc[11]);
    op[3] = make_float4(acc[12], acc[13], acc[14], acc[15]);
  }
}

// wave-per-node; quarter-wave (16 lanes) per edge, float4 per lane.
// Block partials go to per-bucket f64 atomics (256 buckets, 256B apart)
// instead of two global addresses (which serialized the whole kernel).
__global__ __launch_bounds__(256) void agg_k(const float4* __restrict__ hw4, const int* __restrict__ off,
                                             const int2* __restrict__ csr, const float* __restrict__ dinv,
                                             const float4* __restrict__ bias4, float4* __restrict__ out4,
                                             double* __restrict__ buckets, int n) {
  int wid = (int)((blockIdx.x * 256 + threadIdx.x) >> 6);
  int lane = threadIdx.x & 63;
  int g = lane >> 4, q = lane & 15;
  float4 acc = make_float4(0.f, 0.f, 0.f, 0.f);
  float s1 = 0.f, s2 = 0.f;
  if (wid < n) {
    if (g == 0) {
      float di = dinv[wid];
      float w = di * di;
      float4 h = hw4[(size_t)wid * 16 + q];
      float4 b = bias4[q];
      acc.x = fmaf(w, h.x, b.x);
      acc.y = fmaf(w, h.y, b.y);
      acc.z = fmaf(w, h.z, b.z);
      acc.w = fmaf(w, h.w, b.w);
    }
    int e0 = off[wid], e1 = off[wid + 1];
    for (int base = e0; base < e1; base += 16) {
      int eb = base + g * 4;  // this quarter-wave's 4 edges
      int2 c0 = csr[eb + 0];
      int2 c1 = csr[eb + 1];
      int2 c2 = csr[eb + 2];
      int2 c3 = csr[eb + 3];
      int i0 = (eb + 0 < e1) ? c0.x : 0;
      int i1 = (eb + 1 < e1) ? c1.x : 0;
      int i2 = (eb + 2 < e1) ? c2.x : 0;
      int i3 = (eb + 3 < e1) ? c3.x : 0;
      float w0 = (eb + 0 < e1) ? __int_as_float(c0.y) : 0.f;
      float w1 = (eb + 1 < e1) ? __int_as_float(c1.y) : 0.f;
      float w2 = (eb + 2 < e1) ? __int_as_float(c2.y) : 0.f;
      float w3 = (eb + 3 < e1) ? __int_as_float(c3.y) : 0.f;
      float4 v0 = hw4[(size_t)i0 * 16 + q];
      float4 v1 = hw4[(size_t)i1 * 16 + q];
      float4 v2 = hw4[(size_t)i2 * 16 + q];
      float4 v3 = hw4[(size_t)i3 * 16 + q];
      acc.x = fmaf(w0, v0.x, acc.x); acc.y = fmaf(w0, v0.y, acc.y);
      acc.z = fmaf(w0, v0.z, acc.z); acc.w = fmaf(w0, v0.w, acc.w);
      acc.x = fmaf(w1, v1.x, acc.x); acc.y = fmaf(w1, v1.y, acc.y);
      acc.z = fmaf(w1, v1.z, acc.z); acc.w = fmaf(w1, v1.w, acc.w);
      acc.x = fmaf(w2, v2.x, acc.x); acc.y = fmaf(w2, v2.y, acc.y);
      acc.z = fmaf(w2, v2.z, acc.z); acc.w = fmaf(w2, v2.w, acc.w);
      acc.x = fmaf(w3, v3.x, acc.x); acc.y = fmaf(w3, v3.y, acc.y);
      acc.z = fmaf(w3, v3.z, acc.z); acc.w = fmaf(w3, v3.w, acc.w);
    }
    // sum the 4 quarter-wave partials (lanes q, q+16, q+32, q+48)
#pragma unroll
    for (int o = 16; o <= 32; o <<= 1) {
      acc.x += __shfl_xor(acc.x, o);
      acc.y += __shfl_xor(acc.y, o);
      acc.z += __shfl_xor(acc.z, o);
      acc.w += __shfl_xor(acc.w, o);
    }
    if (g == 0) {
      out4[(size_t)wid * 16 + q] = acc;
      s1 = acc.x + acc.y + acc.z + acc.w;
      s2 = acc.x * acc.x + acc.y * acc.y + acc.z * acc.z + acc.w * acc.w;
    }
  }
  // full-wave reduce (only g==0 lanes contributed)
#pragma unroll
  for (int o = 1; o <= 32; o <<= 1) {
    s1 += __shfl_xor(s1, o);
    s2 += __shfl_xor(s2, o);
  }
  __shared__ float red1[4], red2[4];
  int w = threadIdx.x >> 6;
  if (lane == 0) { red1[w] = s1; red2[w] = s2; }
  __syncthreads();
  if (threadIdx.x == 0) {
    double a = (double)red1[0] + (double)red1[1] + (double)red1[2] + (double)red1[3];
    double b = (double)red2[0] + (double)red2[1] + (double)red2[2] + (double)red2[3];
    double* bp = buckets + (size_t)(blockIdx.x & (NBUCK - 1)) * BSTRIDE;
    atomicAdd(&bp[0], a);
    atomicAdd(&bp[1], b);
  }
}

// reduce NBUCK bucket pairs -> stats (one block, 256 threads)
__global__ __launch_bounds__(256) void finalize_k(const double* __restrict__ buckets,
                                                  float* __restrict__ stats, int M) {
  int t = threadIdx.x;
  double a = buckets[(size_t)t * BSTRIDE];
  double b = buckets[(size_t)t * BSTRIDE + 1];
#pragma unroll
  for (int o = 1; o <= 32; o <<= 1) {
    a += __shfl_xor(a, o);
    b += __shfl_xor(b, o);
  }
  __shared__ double ra[4], rb[4];
  if ((t & 63) == 0) { ra[t >> 6] = a; rb[t >> 6] = b; }
  __syncthreads();
  if (t == 0) {
    double s1 = ra[0] + ra[1] + ra[2] + ra[3];
    double s2 = rb[0] + rb[1] + rb[2] + rb[3];
    double mean = s1 / M;
    double var = s2 / M - mean * mean;
    stats[0] = (float)mean;
    stats[1] = (float)rsqrt(var + 1e-5);
  }
}

// final layer: in-place ln+relu on d_out
__global__ __launch_bounds__(256) void norm_relu_k(float* __restrict__ io, const float* __restrict__ lnw,
                                                   const float* __restrict__ lnb, const float* __restrict__ stats,
                                                   int n4) {
  int i = blockIdx.x * 256 + threadIdx.x;
  if (i >= n4) return;
  float mean = stats[0], rstd = stats[1];
  float4 v = ((float4*)io)[i];
  int c = (i & 15) * 4;
  v.x = fmaxf(fmaf((v.x - mean) * rstd, lnw[c + 0], lnb[c + 0]), 0.f);
  v.y = fmaxf(fmaf((v.y - mean) * rstd, lnw[c + 1], lnb[c + 1]), 0.f);
  v.z = fmaxf(fmaf((v.z - mean) * rstd, lnw[c + 2], lnb[c + 2]), 0.f);
  v.w = fmaxf(fmaf((v.w - mean) * rstd, lnw[c + 3], lnb[c + 3]), 0.f);
  ((float4*)io)[i] = v;
}

// ---------------- launch ----------------

extern "C" void kernel_launch(void* const* d_in, const int* in_sizes, int n_in,
                              void* d_out, int out_size, void* d_ws, size_t ws_size,
                              hipStream_t stream) {
  const float* x = (const float*)d_in[0];
  const int* ei = (const int*)d_in[1];
  const float* Ws = (const float*)d_in[2];
  const float* bs = (const float*)d_in[3];
  const float* lnw = (const float*)d_in[4];
  const float* lnb = (const float*)d_in[5];
  float* out = (float*)d_out;

  const int N = in_sizes[0] / DD;
  const int E = in_sizes[1] / 2;
  const int L = in_sizes[2] / (DD * DD);
  const int* srcp = ei;
  const int* dstp = ei + E;

  char* p = (char*)d_ws;
  size_t ofs = 0;
  auto carve = [&](size_t bytes) -> void* {
    void* r = p + ofs;
    ofs = (ofs + bytes + 255) & ~(size_t)255;
    return r;
  };
  int* cnt = (int*)carve((size_t)N * 4);
  int* offv = (int*)carve((size_t)(N + 1) * 4);
  int* cursor = (int*)carve((size_t)N * 4);
  float* dinv = (float*)carve((size_t)N * 4);
  int* bsums = (int*)carve(4096);
  double* buckets = (double*)carve((size_t)NBUCK * BSTRIDE * 8 * 4);  // per-layer sets
  float* stats = (float*)carve(16 * sizeof(float));
  int2* csr = (int2*)carve((size_t)(E + 16) * 8);  // +16: unrolled tail over-read
  float* bufA = (float*)carve((size_t)N * DD * 4);
  float* bufB = (float*)carve((size_t)N * DD * 4);

  hipMemsetAsync(cnt, 0, (size_t)N * 4, stream);
  hipMemsetAsync(buckets, 0, (size_t)NBUCK * BSTRIDE * 8 * 4, stream);

  int gE = (E + 255) / 256;
  int gN = (N + 255) / 256;
  count_deg_k<<<gE, 256, 0, stream>>>(dstp, cnt, E);
  dinv_k<<<gN, 256, 0, stream>>>(cnt, dinv, N);
  int nb = (N + 1023) / 1024;
  scan_a_k<<<nb, 256, 0, stream>>>(cnt, offv, bsums, N);
  scan_b_k<<<1, 64, 0, stream>>>(bsums, nb);
  scan_c_k<<<(N + 256) / 256, 256, 0, stream>>>(offv, cursor, bsums, N, E);
  fill_csr_k<<<gE, 256, 0, stream>>>(srcp, dstp, dinv, cursor, csr, E);

  int gGemm = (N + 63) / 64;
  int gAgg = (N * DD + 255) / 256;  // one wave per node
  for (int l = 0; l < L; ++l) {
    const float* in = (l == 0) ? x : bufB;
    const float* plnw = (l == 0) ? lnw : lnw + (l - 1) * DD;
    const float* plnb = (l == 0) ? lnb : lnb + (l - 1) * DD;
    const float* pst = (l == 0) ? stats : stats + (l - 1) * 2;
    gemm_ln_k<<<gGemm, 256, 0, stream>>>(in, Ws + (size_t)l * DD * DD, bufA, plnw, plnb, pst,
                                         (l > 0) ? 1 : 0, N);
    float* aggout = (l == L - 1) ? out : bufB;
    double* lbuck = buckets + (size_t)l * NBUCK * BSTRIDE;
    agg_k<<<gAgg, 256, 0, stream>>>((const float4*)bufA, offv, csr, dinv,
                                    (const float4*)(bs + (size_t)l * DD), (float4*)aggout,
                                    lbuck, N);
    finalize_k<<<1, 256, 0, stream>>>(lbuck, stats + l * 2, N * DD);
  }
  norm_relu_k<<<(N * (DD / 4) + 255) / 256, 256, 0, stream>>>(out, lnw + (size_t)(L - 1) * DD,
                                                              lnb + (size_t)(L - 1) * DD,
                                                              stats + (L - 1) * 2, N * (DD / 4));
}